// Round 4
// baseline (578.322 us; speedup 1.0000x reference)
//
#include <hip/hip_runtime.h>
#include <hip/hip_bf16.h>
#include <stdint.h>

#define HD 256
#define BM 64
#define APAD 8
#define ASTRIDE (HD + APAD)   // 264 ushorts

typedef __bf16 bf16x8 __attribute__((ext_vector_type(8)));
typedef float f32x4 __attribute__((ext_vector_type(4)));
typedef unsigned short ushort8v __attribute__((ext_vector_type(8)));
typedef unsigned short us4 __attribute__((ext_vector_type(4)));

__device__ __forceinline__ unsigned short f2bf(float f) {
    unsigned int x = __float_as_uint(f);
    unsigned int r = (x + 0x7FFFu + ((x >> 16) & 1u)) >> 16;
    return (unsigned short)r;
}

// ---------------- fused prep: block 0 = prefix scan, blocks 1..64 = weight transpose ----------------
__global__ void prep_kernel(const int* __restrict__ seq_len, int* __restrict__ offsets, int B,
                            const float* __restrict__ Wp, const float* __restrict__ W1,
                            const float* __restrict__ W2,
                            unsigned short* __restrict__ WphT, unsigned short* __restrict__ WpbT,
                            unsigned short* __restrict__ W1T, unsigned short* __restrict__ W2T) {
    int tid = threadIdx.x;
    if (blockIdx.x == 0) {
        // ---- prefix scan of seq_len -> offsets[B+1] ----
        __shared__ int sums[256];
        int per = (B + 255) / 256;
        int b0 = tid * per;
        int local[32];
        int tot = 0;
        for (int i = 0; i < per && i < 32; ++i) {
            int b = b0 + i;
            int v = (b < B) ? seq_len[b] : 0;
            local[i] = tot;
            tot += v;
        }
        sums[tid] = tot;
        __syncthreads();
        for (int off = 1; off < 256; off <<= 1) {
            int v = (tid >= off) ? sums[tid - off] : 0;
            __syncthreads();
            sums[tid] += v;
            __syncthreads();
        }
        int start = sums[tid] - tot;
        for (int i = 0; i < per && i < 32; ++i) {
            int b = b0 + i;
            if (b < B) offsets[b] = start + local[i];
        }
        if (tid == 255) offsets[B] = sums[255];
    } else {
        // ---- coalesced LDS-tile transpose+convert weights to bf16 [N][K] ----
        __shared__ unsigned short tile[64][72];
        int bid = blockIdx.x - 1;
        const float* src;
        unsigned short* dst;
        int k0, n0, kk;
        if (bid < 32) {            // W_pos: 512 k-rows
            int tk = bid >> 2, tn = bid & 3;
            src = Wp; k0 = tk * 64; n0 = tn * 64;
            if (k0 < 256) { dst = WphT; kk = k0; }
            else          { dst = WpbT; kk = k0 - 256; }
        } else if (bid < 48) {
            int b2 = bid - 32;
            src = W1; k0 = (b2 >> 2) * 64; n0 = (b2 & 3) * 64;
            dst = W1T; kk = k0;
        } else {
            int b2 = bid - 48;
            src = W2; k0 = (b2 >> 2) * 64; n0 = (b2 & 3) * 64;
            dst = W2T; kk = k0;
        }
        {
            int col = tid & 63;
            int rbase = tid >> 6;          // 0..3
            #pragma unroll
            for (int i = 0; i < 16; ++i) {
                int lrow = rbase + 4 * i;  // 0..63
                tile[lrow][col] = f2bf(src[(size_t)(k0 + lrow) * HD + n0 + col]);
            }
        }
        __syncthreads();
        {
            int nl = tid >> 2;             // 0..63
            int kc0 = (tid & 3) * 16;      // 0,16,32,48
            #pragma unroll
            for (int j = 0; j < 4; ++j) {
                int kc = kc0 + 4 * j;
                us4 v;
                v[0] = tile[kc + 0][nl];
                v[1] = tile[kc + 1][nl];
                v[2] = tile[kc + 2][nl];
                v[3] = tile[kc + 3][nl];
                *reinterpret_cast<us4*>(dst + (size_t)(n0 + nl) * HD + kk + kc) = v;
            }
        }
    }
}

// ---------------- wave-per-session mean + seg fill + bf16 hidden copy ----------------
// One 64-lane wave streams one session: lane owns one float4 column, rows are
// contiguous 1KB reads. 4 sessions per block. Pure streaming, no LDS reduce.
__global__ __launch_bounds__(256) void mean_kernel(
    const float* __restrict__ hidden, const int* __restrict__ offsets,
    unsigned short* __restrict__ mean_bf, unsigned short* __restrict__ hb,
    int* __restrict__ seg, int B) {
    int wave = threadIdx.x >> 6, lane = threadIdx.x & 63;
    int b = blockIdx.x * 4 + wave;
    if (b >= B) return;
    int s = offsets[b], e = offsets[b + 1];
    for (int t = s + lane; t < e; t += 64) seg[t] = b;
    int c4 = lane * 4;
    float4 acc = {0.f, 0.f, 0.f, 0.f};
    if (hb) {
        for (int t = s; t < e; ++t) {
            const float4 v = *reinterpret_cast<const float4*>(hidden + (size_t)t * HD + c4);
            acc.x += v.x; acc.y += v.y; acc.z += v.z; acc.w += v.w;
            us4 pk;
            pk[0] = f2bf(v.x); pk[1] = f2bf(v.y); pk[2] = f2bf(v.z); pk[3] = f2bf(v.w);
            *reinterpret_cast<us4*>(hb + (size_t)t * HD + c4) = pk;
        }
    } else {
        for (int t = s; t < e; ++t) {
            const float4 v = *reinterpret_cast<const float4*>(hidden + (size_t)t * HD + c4);
            acc.x += v.x; acc.y += v.y; acc.z += v.z; acc.w += v.w;
        }
    }
    float inv = 1.0f / (float)(e - s);
    us4 pk;
    pk[0] = f2bf(acc.x * inv);
    pk[1] = f2bf(acc.y * inv);
    pk[2] = f2bf(acc.z * inv);
    pk[3] = f2bf(acc.w * inv);
    *reinterpret_cast<us4*>(mean_bf + (size_t)b * HD + c4) = pk;
}

// ---------------- fused small GEMMs (u and P2), M-tile = 16 ----------------
__global__ __launch_bounds__(256) void small_gemm_kernel(
    const unsigned short* __restrict__ mean_bf, int Mu, int nbu,
    const float* __restrict__ pos_table, int Mp,
    const unsigned short* __restrict__ W1T, const unsigned short* __restrict__ WpbT,
    const float* __restrict__ b1, const float* __restrict__ b2, const float* __restrict__ bp,
    float* __restrict__ u, float* __restrict__ P2) {
    __shared__ __align__(16) unsigned short As[16][ASTRIDE];
    int tid = threadIdx.x;
    bool isU = (int)blockIdx.x < nbu;
    int m0 = isU ? blockIdx.x * 16 : (blockIdx.x - nbu) * 16;
    int M  = isU ? Mu : Mp;
    const unsigned short* BT = isU ? W1T : WpbT;
    float* out = isU ? u : P2;

    {   // stage 16 rows x 256 cols
        int row = tid >> 4;
        int colg = (tid & 15) * 16;
        int m = m0 + row;
        if (isU) {
            ushort8v v0 = {0,0,0,0,0,0,0,0}, v1 = {0,0,0,0,0,0,0,0};
            if (m < M) {
                v0 = *reinterpret_cast<const ushort8v*>(mean_bf + (size_t)m * HD + colg);
                v1 = *reinterpret_cast<const ushort8v*>(mean_bf + (size_t)m * HD + colg + 8);
            }
            *reinterpret_cast<ushort8v*>(&As[row][colg])     = v0;
            *reinterpret_cast<ushort8v*>(&As[row][colg + 8]) = v1;
        } else {
            float4 f[4] = {{0,0,0,0},{0,0,0,0},{0,0,0,0},{0,0,0,0}};
            if (m < M) {
                const float4* p = reinterpret_cast<const float4*>(pos_table + (size_t)m * HD + colg);
                f[0] = p[0]; f[1] = p[1]; f[2] = p[2]; f[3] = p[3];
            }
            ushort8v v0, v1;
            v0[0]=f2bf(f[0].x); v0[1]=f2bf(f[0].y); v0[2]=f2bf(f[0].z); v0[3]=f2bf(f[0].w);
            v0[4]=f2bf(f[1].x); v0[5]=f2bf(f[1].y); v0[6]=f2bf(f[1].z); v0[7]=f2bf(f[1].w);
            v1[0]=f2bf(f[2].x); v1[1]=f2bf(f[2].y); v1[2]=f2bf(f[2].z); v1[3]=f2bf(f[2].w);
            v1[4]=f2bf(f[3].x); v1[5]=f2bf(f[3].y); v1[6]=f2bf(f[3].z); v1[7]=f2bf(f[3].w);
            *reinterpret_cast<ushort8v*>(&As[row][colg])     = v0;
            *reinterpret_cast<ushort8v*>(&As[row][colg + 8]) = v1;
        }
    }
    __syncthreads();

    int wave = tid >> 6, lane = tid & 63, quad = lane >> 4, cc = lane & 15;
    int nb = wave * 64;
    f32x4 acc4[4];
    for (int i = 0; i < 4; ++i) acc4[i] = (f32x4){0.f, 0.f, 0.f, 0.f};

    bf16x8 wfp[4];
    for (int nf = 0; nf < 4; ++nf)
        wfp[nf] = *reinterpret_cast<const bf16x8*>(BT + (size_t)(nb + nf * 16 + cc) * HD + quad * 8);
    for (int kc8 = 0; kc8 < 8; ++kc8) {
        int kc = kc8 * 32;
        bf16x8 wfc[4];
        for (int nf = 0; nf < 4; ++nf) wfc[nf] = wfp[nf];
        if (kc8 < 7)
            for (int nf = 0; nf < 4; ++nf)
                wfp[nf] = *reinterpret_cast<const bf16x8*>(BT + (size_t)(nb + nf * 16 + cc) * HD + kc + 32 + quad * 8);
        bf16x8 af = *reinterpret_cast<const bf16x8*>(&As[cc][kc + quad * 8]);
        for (int nf = 0; nf < 4; ++nf)
            acc4[nf] = __builtin_amdgcn_mfma_f32_16x16x32_bf16(af, wfc[nf], acc4[nf], 0, 0, 0);
    }
    for (int nf = 0; nf < 4; ++nf)
        for (int r = 0; r < 4; ++r) {
            int row = m0 + quad * 4 + r;
            int col = nb + nf * 16 + cc;
            if (row < M) {
                float bias = isU ? (b1[col] + b2[col]) : bp[col];
                out[(size_t)row * HD + col] = acc4[nf][r] + bias;
            }
        }
}

// ---------------- fused main kernel: 512 threads / 8 waves, BM=64 tokens ----------------
// GEMM1: D row = h (A = WphT), col = token. Wave w owns h rows [w*32, w*32+32).
// GEMM2 (swapped): D row = n (A = W2T), col = token. Wave w owns n rows [w*32, w*32+32).
// Scattered P2[rp]/u[seg] gathers are issued EARLY (before barrier / before GEMM2 K-loop)
// so their ~200-900cy latency drains under MFMA / barrier wait instead of serially.
__global__ __launch_bounds__(512, 4) void main_kernel(
    const float* __restrict__ hidden, const unsigned short* __restrict__ hb, int T,
    const unsigned short* __restrict__ WphT,
    const unsigned short* __restrict__ W2T,
    const float* __restrict__ P2,
    const float* __restrict__ u,
    const float* __restrict__ qw, const float* __restrict__ qb,
    const int* __restrict__ rp, const int* __restrict__ seg,
    float* __restrict__ alpha) {
    __shared__ __align__(16) unsigned short Ah[BM][ASTRIDE];   // A tile, then Ph in place
    __shared__ int rp_s[BM];
    __shared__ int seg_s[BM];
    __shared__ float alpha_s[BM];

    int tid = threadIdx.x;
    int t0 = blockIdx.x * BM;
    int wave = tid >> 6, lane = tid & 63, quad = lane >> 4, cc = lane & 15;
    int mb = wave * 32;    // h-slice base (GEMM1) / n-slice base (GEMM2)

    // ---- preload GEMM1 weight frags for kc=0 (in flight during staging) ----
    bf16x8 afp[2];
    #pragma unroll
    for (int mf = 0; mf < 2; ++mf)
        afp[mf] = *reinterpret_cast<const bf16x8*>(WphT + (size_t)(mb + mf * 16 + cc) * HD + quad * 8);

    // ---- stage hidden tile -> LDS (512 threads: 4 x 16B chunks each) ----
    {
        int row = tid >> 3;
        int t = t0 + row;
        if (hb) {
            #pragma unroll
            for (int i = 0; i < 4; ++i) {
                int cg = (tid & 7) * 8 + 64 * i;
                ushort8v v = {0,0,0,0,0,0,0,0};
                if (t < T) v = *reinterpret_cast<const ushort8v*>(hb + (size_t)t * HD + cg);
                *reinterpret_cast<ushort8v*>(&Ah[row][cg]) = v;
            }
        } else {
            #pragma unroll
            for (int i = 0; i < 4; ++i) {
                int cg = (tid & 7) * 8 + 64 * i;
                float4 f0 = {0,0,0,0}, f1 = {0,0,0,0};
                if (t < T) {
                    const float4* p = reinterpret_cast<const float4*>(hidden + (size_t)t * HD + cg);
                    f0 = p[0]; f1 = p[1];
                }
                ushort8v pk;
                pk[0] = f2bf(f0.x); pk[1] = f2bf(f0.y); pk[2] = f2bf(f0.z); pk[3] = f2bf(f0.w);
                pk[4] = f2bf(f1.x); pk[5] = f2bf(f1.y); pk[6] = f2bf(f1.z); pk[7] = f2bf(f1.w);
                *reinterpret_cast<ushort8v*>(&Ah[row][cg]) = pk;
            }
        }
    }
    if (tid < BM) {
        int t = t0 + tid;
        rp_s[tid]  = (t < T) ? rp[t] : 0;
        seg_s[tid] = (t < T) ? seg[t] : 0;
        alpha_s[tid] = qb[0];
    }
    __syncthreads();

    f32x4 acc[2][4];
    #pragma unroll
    for (int i = 0; i < 2; ++i)
        #pragma unroll
        for (int j = 0; j < 4; ++j) acc[i][j] = (f32x4){0.f, 0.f, 0.f, 0.f};

    // ---- GEMM1 (transposed): rows = h, cols = token; weights pipelined ----
    for (int kc8 = 0; kc8 < 8; ++kc8) {
        int kc = kc8 * 32;
        bf16x8 afc[2];
        #pragma unroll
        for (int mf = 0; mf < 2; ++mf) afc[mf] = afp[mf];
        if (kc8 < 7)
            #pragma unroll
            for (int mf = 0; mf < 2; ++mf)
                afp[mf] = *reinterpret_cast<const bf16x8*>(WphT + (size_t)(mb + mf * 16 + cc) * HD + kc + 32 + quad * 8);
        bf16x8 bfr[4];
        #pragma unroll
        for (int nf = 0; nf < 4; ++nf)
            bfr[nf] = *reinterpret_cast<const bf16x8*>(&Ah[nf * 16 + cc][kc + quad * 8]);
        #pragma unroll
        for (int mf = 0; mf < 2; ++mf)
            #pragma unroll
            for (int nf = 0; nf < 4; ++nf)
                acc[mf][nf] = __builtin_amdgcn_mfma_f32_16x16x32_bf16(afc[mf], bfr[nf], acc[mf][nf], 0, 0, 0);
    }

    // ---- prefetch scattered P2 rows BEFORE the barrier (no LDS touched; drains under it) ----
    f32x4 p2v[4][2];
    #pragma unroll
    for (int nf = 0; nf < 4; ++nf) {
        const float* p2row = P2 + (size_t)rp_s[nf * 16 + cc] * HD;
        #pragma unroll
        for (int mf = 0; mf < 2; ++mf)
            p2v[nf][mf] = *reinterpret_cast<const f32x4*>(p2row + mb + mf * 16 + quad * 4);
    }
    __syncthreads();   // all LDS reads of the A tile done

    // ---- preload GEMM2 weight frags kc=0 (W2T rows = n; A-operand after swap) ----
    bf16x8 wfp[2];
    #pragma unroll
    for (int mf = 0; mf < 2; ++mf)
        wfp[mf] = *reinterpret_cast<const bf16x8*>(W2T + (size_t)(mb + mf * 16 + cc) * HD + quad * 8);

    // ---- epilogue 1: Ph[token][h] = tanh(acc + P2[rp][h]) ----
    #pragma unroll
    for (int nf = 0; nf < 4; ++nf) {
        int token = nf * 16 + cc;
        #pragma unroll
        for (int mf = 0; mf < 2; ++mf) {
            int h0 = mb + mf * 16 + quad * 4;
            us4 pk;
            {
                float v0 = acc[mf][nf][0] + p2v[nf][mf][0];
                float v1 = acc[mf][nf][1] + p2v[nf][mf][1];
                float v2 = acc[mf][nf][2] + p2v[nf][mf][2];
                float v3 = acc[mf][nf][3] + p2v[nf][mf][3];
                float e0 = __expf(2.f * v0), e1 = __expf(2.f * v1);
                float e2 = __expf(2.f * v2), e3 = __expf(2.f * v3);
                pk[0] = f2bf(1.f - 2.f / (e0 + 1.f));
                pk[1] = f2bf(1.f - 2.f / (e1 + 1.f));
                pk[2] = f2bf(1.f - 2.f / (e2 + 1.f));
                pk[3] = f2bf(1.f - 2.f / (e3 + 1.f));
            }
            *reinterpret_cast<us4*>(&Ah[token][h0]) = pk;
            acc[mf][nf] = (f32x4){0.f, 0.f, 0.f, 0.f};
        }
    }
    __syncthreads();

    // ---- prefetch scattered u rows + qw BEFORE the GEMM2 K-loop (hidden under MFMA) ----
    f32x4 uv[4][2];
    #pragma unroll
    for (int nf = 0; nf < 4; ++nf) {
        const float* urow = u + (size_t)seg_s[nf * 16 + cc] * HD;
        #pragma unroll
        for (int mf = 0; mf < 2; ++mf)
            uv[nf][mf] = *reinterpret_cast<const f32x4*>(urow + mb + mf * 16 + quad * 4);
    }
    f32x4 qv[2];
    #pragma unroll
    for (int mf = 0; mf < 2; ++mf)
        qv[mf] = *reinterpret_cast<const f32x4*>(qw + mb + mf * 16 + quad * 4);

    // ---- GEMM2 (swapped): A = W2T (rows n), B = Ph tokens; D row = n, col = token ----
    for (int kc8 = 0; kc8 < 8; ++kc8) {
        int kc = kc8 * 32;
        bf16x8 wfc[2];
        #pragma unroll
        for (int mf = 0; mf < 2; ++mf) wfc[mf] = wfp[mf];
        if (kc8 < 7)
            #pragma unroll
            for (int mf = 0; mf < 2; ++mf)
                wfp[mf] = *reinterpret_cast<const bf16x8*>(W2T + (size_t)(mb + mf * 16 + cc) * HD + kc + 32 + quad * 8);
        #pragma unroll
        for (int nf = 0; nf < 4; ++nf) {
            bf16x8 af = *reinterpret_cast<const bf16x8*>(&Ah[nf * 16 + cc][kc + quad * 8]);
            #pragma unroll
            for (int mf = 0; mf < 2; ++mf)
                acc[mf][nf] = __builtin_amdgcn_mfma_f32_16x16x32_bf16(wfc[mf], af, acc[mf][nf], 0, 0, 0);
        }
    }

    // ---- epilogue 2: alpha[token] += sum_n sigmoid(acc + u[seg][n]) * qw[n] ----
    #pragma unroll
    for (int nf = 0; nf < 4; ++nf) {
        int token = nf * 16 + cc;
        float s = 0.f;
        #pragma unroll
        for (int mf = 0; mf < 2; ++mf) {
            #pragma unroll
            for (int r = 0; r < 4; ++r) {
                float g = acc[mf][nf][r] + uv[nf][mf][r];
                g = 1.0f / (1.0f + __expf(-g));
                s += g * qv[mf][r];
            }
        }
        s += __shfl_xor(s, 16);
        s += __shfl_xor(s, 32);
        if (quad == 0) atomicAdd(&alpha_s[token], s);
    }
    __syncthreads();
    if (tid < BM) {
        int t = t0 + tid;
        if (t < T) alpha[t] = alpha_s[tid];
    }
}

// ---------------- wave-per-session weighted segment sum -> d_out ----------------
// One wave per session: lane owns one 4-col group, rows stream sequentially.
// No LDS, no atomics, uniform alpha scalar per row.
__global__ __launch_bounds__(256) void hs_kernel(
    const float* __restrict__ hidden, const unsigned short* __restrict__ hb,
    const float* __restrict__ alpha,
    const int* __restrict__ offsets, float* __restrict__ out, int B) {
    int wave = threadIdx.x >> 6, lane = threadIdx.x & 63;
    int b = blockIdx.x * 4 + wave;
    if (b >= B) return;
    int s = offsets[b], e = offsets[b + 1];
    int c4 = lane * 4;
    float4 acc = {0.f, 0.f, 0.f, 0.f};
    if (hb) {
        for (int t = s; t < e; ++t) {
            float a = alpha[t];
            us4 v = *reinterpret_cast<const us4*>(hb + (size_t)t * HD + c4);
            acc.x += a * __uint_as_float(((unsigned)v[0]) << 16);
            acc.y += a * __uint_as_float(((unsigned)v[1]) << 16);
            acc.z += a * __uint_as_float(((unsigned)v[2]) << 16);
            acc.w += a * __uint_as_float(((unsigned)v[3]) << 16);
        }
    } else {
        for (int t = s; t < e; ++t) {
            float a = alpha[t];
            const float4 v = *reinterpret_cast<const float4*>(hidden + (size_t)t * HD + c4);
            acc.x += a * v.x; acc.y += a * v.y; acc.z += a * v.z; acc.w += a * v.w;
        }
    }
    *reinterpret_cast<float4*>(out + (size_t)b * HD + c4) = acc;
}

extern "C" void kernel_launch(void* const* d_in, const int* in_sizes, int n_in,
                              void* d_out, int out_size, void* d_ws, size_t ws_size,
                              hipStream_t stream) {
    (void)n_in; (void)out_size;
    const float* hidden    = (const float*)d_in[0];
    const float* pos_table = (const float*)d_in[1];
    const float* W_pos     = (const float*)d_in[2];
    const float* b_pos     = (const float*)d_in[3];
    const float* W1        = (const float*)d_in[4];
    const float* b1        = (const float*)d_in[5];
    const float* W2        = (const float*)d_in[6];
    const float* b2        = (const float*)d_in[7];
    const float* qw        = (const float*)d_in[8];
    const float* qb        = (const float*)d_in[9];
    const int* seq_len     = (const int*)d_in[10];
    const int* reverse_pos = (const int*)d_in[11];

    int T  = in_sizes[0] / HD;
    int B  = in_sizes[10];
    int NP = in_sizes[1] / HD;

    char* ws = (char*)d_ws;
    char* ws_end = ws + ws_size;
    auto carve = [&](size_t bytes) -> char* {
        char* p = ws;
        ws += (bytes + 255) & ~(size_t)255;
        return p;
    };
    int* offsets          = (int*)carve((size_t)(B + 1) * sizeof(int));
    int* seg              = (int*)carve((size_t)T * sizeof(int));
    unsigned short* meanb = (unsigned short*)carve((size_t)B * HD * 2);
    float* u              = (float*)carve((size_t)B * HD * sizeof(float));
    float* P2             = (float*)carve((size_t)NP * HD * sizeof(float));
    unsigned short* WphT  = (unsigned short*)carve((size_t)HD * HD * 2);
    unsigned short* WpbT  = (unsigned short*)carve((size_t)HD * HD * 2);
    unsigned short* W1T   = (unsigned short*)carve((size_t)HD * HD * 2);
    unsigned short* W2T   = (unsigned short*)carve((size_t)HD * HD * 2);
    float* alpha          = (float*)carve((size_t)T * sizeof(float));
    unsigned short* hb    = nullptr;
    if ((size_t)(ws_end - ws) >= (size_t)T * HD * 2 + 256)
        hb = (unsigned short*)carve((size_t)T * HD * 2);

    int nbu = (B + 15) / 16;
    int nbp = (NP + 15) / 16;
    int nsb = (B + 3) / 4;

    prep_kernel<<<65, 256, 0, stream>>>(seq_len, offsets, B, W_pos, W1, W2,
                                        WphT, WpbT, W1T, W2T);
    mean_kernel<<<nsb, 256, 0, stream>>>(hidden, offsets, meanb, hb, seg, B);
    small_gemm_kernel<<<nbu + nbp, 256, 0, stream>>>(meanb, B, nbu, pos_table, NP,
                                                     W1T, WpbT, b1, b2, b_pos, u, P2);
    main_kernel<<<(T + BM - 1) / BM, 512, 0, stream>>>(hidden, hb, T, WphT, W2T, P2, u, qw, qb,
                                                       reverse_pos, seg, alpha);
    hs_kernel<<<nsb, 256, 0, stream>>>(hidden, hb, alpha, offsets, (float*)d_out, B);
}

// Round 5
// 569.045 us; speedup vs baseline: 1.0163x; 1.0163x over previous
//
#include <hip/hip_runtime.h>
#include <hip/hip_bf16.h>
#include <stdint.h>

#define HD 256
#define BM 128          // tokens per block = one session-aligned group (len<=99 < BM assumed)
#define MAXS 16         // max sessions per group (min len 10 -> <=12, guard at 16)
#define APAD 8
#define ASTRIDE (HD + APAD)    // 264 ushorts
#define USTRIDE (HD + 4)       // 260 floats (u overlay stride)

typedef __bf16 bf16x8 __attribute__((ext_vector_type(8)));
typedef float f32x4 __attribute__((ext_vector_type(4)));
typedef unsigned short ushort8v __attribute__((ext_vector_type(8)));
typedef unsigned short us4 __attribute__((ext_vector_type(4)));

__device__ __forceinline__ unsigned short f2bf(float f) {
    unsigned int x = __float_as_uint(f);
    unsigned int r = (x + 0x7FFFu + ((x >> 16) & 1u)) >> 16;
    return (unsigned short)r;
}
__device__ __forceinline__ float bf2f(unsigned short u) {
    return __uint_as_float(((unsigned)u) << 16);
}

// ---------------- prep: block 0 = scan + session-group partition; blocks 1..64 = transpose ----------------
__global__ void prep_kernel(const int* __restrict__ seq_len, int* __restrict__ offsets, int B,
                            int* __restrict__ grp_off, int* __restrict__ grp_meta,
                            const float* __restrict__ Wp, const float* __restrict__ W1,
                            const float* __restrict__ W2,
                            unsigned short* __restrict__ WphT, unsigned short* __restrict__ WpbT,
                            unsigned short* __restrict__ W1T, unsigned short* __restrict__ W2T) {
    int tid = threadIdx.x;
    if (blockIdx.x == 0) {
        __shared__ int sums[256];
        int per = (B + 255) / 256;
        int b0 = tid * per;
        int local[32];
        int tot = 0;
        for (int i = 0; i < per && i < 32; ++i) {
            int b = b0 + i;
            int v = (b < B) ? seq_len[b] : 0;
            local[i] = tot;
            tot += v;
        }
        sums[tid] = tot;
        __syncthreads();
        for (int off = 1; off < 256; off <<= 1) {
            int v = (tid >= off) ? sums[tid - off] : 0;
            __syncthreads();
            sums[tid] += v;
            __syncthreads();
        }
        int start = sums[tid] - tot;
        for (int i = 0; i < per && i < 32; ++i) {
            int b = b0 + i;
            if (b < B) offsets[b] = start + local[i];
        }
        if (tid == 255) offsets[B] = sums[255];

        // ---- parallel chunked-greedy partition: each thread packs its own chunk of sessions,
        //      forcing a group boundary at chunk seams (valid, slight fill loss only) ----
        int starts[32];
        int ng = 0;
        {
            int cur = 0, cnt = 0;
            for (int i = 0; i < per && i < 32; ++i) {
                int b = b0 + i;
                if (b >= B) break;
                int nxt = (i + 1 < per && i + 1 < 32) ? local[i + 1] : tot;
                int len = nxt - local[i];
                if (i == 0 || cur + len > BM || cnt == MAXS) { starts[ng++] = b; cur = 0; cnt = 0; }
                cur += len; cnt++;
            }
        }
        __syncthreads();
        sums[tid] = ng;
        __syncthreads();
        for (int off = 1; off < 256; off <<= 1) {
            int v = (tid >= off) ? sums[tid - off] : 0;
            __syncthreads();
            sums[tid] += v;
            __syncthreads();
        }
        int gbase = sums[tid] - ng;
        for (int j = 0; j < ng; ++j) grp_off[gbase + j] = starts[j];
        if (tid == 255) { grp_meta[0] = sums[255]; grp_off[sums[255]] = B; }
    } else {
        // ---- coalesced LDS-tile transpose+convert weights to bf16 [N][K] ----
        __shared__ unsigned short tile[64][72];
        int bid = blockIdx.x - 1;
        const float* src;
        unsigned short* dst;
        int k0, n0, kk;
        if (bid < 32) {
            int tk = bid >> 2, tn = bid & 3;
            src = Wp; k0 = tk * 64; n0 = tn * 64;
            if (k0 < 256) { dst = WphT; kk = k0; }
            else          { dst = WpbT; kk = k0 - 256; }
        } else if (bid < 48) {
            int b2 = bid - 32;
            src = W1; k0 = (b2 >> 2) * 64; n0 = (b2 & 3) * 64;
            dst = W1T; kk = k0;
        } else {
            int b2 = bid - 48;
            src = W2; k0 = (b2 >> 2) * 64; n0 = (b2 & 3) * 64;
            dst = W2T; kk = k0;
        }
        {
            int col = tid & 63;
            int rbase = tid >> 6;
            #pragma unroll
            for (int i = 0; i < 16; ++i) {
                int lrow = rbase + 4 * i;
                tile[lrow][col] = f2bf(src[(size_t)(k0 + lrow) * HD + n0 + col]);
            }
        }
        __syncthreads();
        {
            int nl = tid >> 2;
            int kc0 = (tid & 3) * 16;
            #pragma unroll
            for (int j = 0; j < 4; ++j) {
                int kc = kc0 + 4 * j;
                us4 v;
                v[0] = tile[kc + 0][nl];
                v[1] = tile[kc + 1][nl];
                v[2] = tile[kc + 2][nl];
                v[3] = tile[kc + 3][nl];
                *reinterpret_cast<us4*>(dst + (size_t)(n0 + nl) * HD + kk + kc) = v;
            }
        }
    }
}

// ---------------- P2[m] = tanh-input table: pos_table[m] @ WpbT^T + b_pos ----------------
__global__ __launch_bounds__(256) void p2_kernel(
    const float* __restrict__ pos_table, int Mp,
    const unsigned short* __restrict__ WpbT, const float* __restrict__ bp,
    float* __restrict__ P2) {
    __shared__ __align__(16) unsigned short As[16][ASTRIDE];
    int tid = threadIdx.x;
    int m0 = blockIdx.x * 16;
    {
        int row = tid >> 4;
        int colg = (tid & 15) * 16;
        int m = m0 + row;
        float4 f[4] = {{0,0,0,0},{0,0,0,0},{0,0,0,0},{0,0,0,0}};
        if (m < Mp) {
            const float4* p = reinterpret_cast<const float4*>(pos_table + (size_t)m * HD + colg);
            f[0] = p[0]; f[1] = p[1]; f[2] = p[2]; f[3] = p[3];
        }
        ushort8v v0, v1;
        v0[0]=f2bf(f[0].x); v0[1]=f2bf(f[0].y); v0[2]=f2bf(f[0].z); v0[3]=f2bf(f[0].w);
        v0[4]=f2bf(f[1].x); v0[5]=f2bf(f[1].y); v0[6]=f2bf(f[1].z); v0[7]=f2bf(f[1].w);
        v1[0]=f2bf(f[2].x); v1[1]=f2bf(f[2].y); v1[2]=f2bf(f[2].z); v1[3]=f2bf(f[2].w);
        v1[4]=f2bf(f[3].x); v1[5]=f2bf(f[3].y); v1[6]=f2bf(f[3].z); v1[7]=f2bf(f[3].w);
        *reinterpret_cast<ushort8v*>(&As[row][colg])     = v0;
        *reinterpret_cast<ushort8v*>(&As[row][colg + 8]) = v1;
    }
    __syncthreads();

    int wave = tid >> 6, lane = tid & 63, quad = lane >> 4, cc = lane & 15;
    int nb = wave * 64;
    f32x4 acc4[4];
    for (int i = 0; i < 4; ++i) acc4[i] = (f32x4){0.f, 0.f, 0.f, 0.f};
    bf16x8 wfp[4];
    for (int nf = 0; nf < 4; ++nf)
        wfp[nf] = *reinterpret_cast<const bf16x8*>(WpbT + (size_t)(nb + nf * 16 + cc) * HD + quad * 8);
    for (int kc8 = 0; kc8 < 8; ++kc8) {
        int kc = kc8 * 32;
        bf16x8 wfc[4];
        for (int nf = 0; nf < 4; ++nf) wfc[nf] = wfp[nf];
        if (kc8 < 7)
            for (int nf = 0; nf < 4; ++nf)
                wfp[nf] = *reinterpret_cast<const bf16x8*>(WpbT + (size_t)(nb + nf * 16 + cc) * HD + kc + 32 + quad * 8);
        bf16x8 af = *reinterpret_cast<const bf16x8*>(&As[cc][kc + quad * 8]);
        for (int nf = 0; nf < 4; ++nf)
            acc4[nf] = __builtin_amdgcn_mfma_f32_16x16x32_bf16(af, wfc[nf], acc4[nf], 0, 0, 0);
    }
    for (int nf = 0; nf < 4; ++nf)
        for (int r = 0; r < 4; ++r) {
            int row = m0 + quad * 4 + r;
            int col = nb + nf * 16 + cc;
            if (row < Mp) P2[(size_t)row * HD + col] = acc4[nf][r] + bp[col];
        }
}

// ---------------- mega-fused main: one block = one session group (<=128 tokens, <=16 sessions) ----------------
// Phases: stage fp32->bf16 | per-session means (LDS) | GEMM1 (WphT x hidden^T) | u-GEMM (means x W1T)
// | ep1 tanh -> Ph in place | GEMM2 (W2T x Ph^T) | u spill to LDS overlay | ep2 alpha | fp32 hs tail.
__global__ __launch_bounds__(512, 4) void main_kernel(
    const float* __restrict__ hidden,
    const unsigned short* __restrict__ WphT,
    const unsigned short* __restrict__ W1T,
    const unsigned short* __restrict__ W2T,
    const float* __restrict__ P2,
    const float* __restrict__ b1, const float* __restrict__ b2,
    const float* __restrict__ qw, const float* __restrict__ qb,
    const int* __restrict__ rp, const int* __restrict__ offsets,
    const int* __restrict__ grp_off, const int* __restrict__ grp_meta,
    float* __restrict__ out) {
    __shared__ __align__(16) unsigned short Ah[BM][ASTRIDE];   // hidden bf16 -> Ph -> u overlay (fp32)
    __shared__ __align__(16) unsigned short Ms[MAXS][ASTRIDE]; // session means bf16
    __shared__ float alpha_s[BM];
    __shared__ int rp_s[BM];
    __shared__ int seg_l[BM];
    __shared__ int sess_st[MAXS + 1];

    int NG = grp_meta[0];
    if ((int)blockIdx.x >= NG) return;
    int tid = threadIdx.x;
    int b0  = grp_off[blockIdx.x];
    int b1e = grp_off[blockIdx.x + 1];
    int nsess = b1e - b0;
    int t0g = offsets[b0];
    int nrows = offsets[b1e] - t0g;

    int wv = tid >> 6, lane = tid & 63, quad = lane >> 4, cc = lane & 15;
    int mb = wv * 32;   // h-slice (GEMM1) / n-slice (GEMM2, u-GEMM)

    if (tid <= nsess) sess_st[tid] = offsets[b0 + tid] - t0g;
    if (tid < BM) {
        alpha_s[tid] = qb[0];
        rp_s[tid] = (tid < nrows) ? rp[t0g + tid] : 0;
    }

    // preload GEMM1 weight frags kc=0 (in flight during staging)
    bf16x8 afp[2];
    #pragma unroll
    for (int mf = 0; mf < 2; ++mf)
        afp[mf] = *reinterpret_cast<const bf16x8*>(WphT + (size_t)(mb + mf * 16 + cc) * HD + quad * 8);

    // ---- stage hidden fp32 -> bf16 tile (pad rows zeroed) ----
    {
        int row = tid >> 2;
        #pragma unroll
        for (int i = 0; i < 8; ++i) {
            int cg = (tid & 3) * 8 + 32 * i;
            float4 f0 = {0,0,0,0}, f1 = {0,0,0,0};
            if (row < nrows) {
                const float4* p = reinterpret_cast<const float4*>(hidden + (size_t)(t0g + row) * HD + cg);
                f0 = p[0]; f1 = p[1];
            }
            ushort8v pk;
            pk[0] = f2bf(f0.x); pk[1] = f2bf(f0.y); pk[2] = f2bf(f0.z); pk[3] = f2bf(f0.w);
            pk[4] = f2bf(f1.x); pk[5] = f2bf(f1.y); pk[6] = f2bf(f1.z); pk[7] = f2bf(f1.w);
            *reinterpret_cast<ushort8v*>(&Ah[row][cg]) = pk;
        }
    }
    __syncthreads();   // B1: Ah + sess_st ready

    // ---- seg_l (binary search over sess_st) ----
    if (tid < BM) {
        int s = 0;
        #pragma unroll
        for (int stp = 8; stp >= 1; stp >>= 1)
            if (s + stp < nsess && sess_st[s + stp] <= tid) s += stp;
        seg_l[tid] = (tid < nrows) ? s : 0;
    }
    // ---- per-session means from staged tile (wave per session, lane owns 4 cols) ----
    for (int s = wv; s < nsess; s += 8) {
        int st = sess_st[s], en = sess_st[s + 1];
        float a0 = 0.f, a1 = 0.f, a2 = 0.f, a3 = 0.f;
        for (int r = st; r < en; ++r) {
            us4 v = *reinterpret_cast<const us4*>(&Ah[r][lane * 4]);
            a0 += bf2f(v[0]); a1 += bf2f(v[1]); a2 += bf2f(v[2]); a3 += bf2f(v[3]);
        }
        float inv = 1.0f / (float)(en - st);
        us4 pk;
        pk[0] = f2bf(a0 * inv); pk[1] = f2bf(a1 * inv);
        pk[2] = f2bf(a2 * inv); pk[3] = f2bf(a3 * inv);
        *reinterpret_cast<us4*>(&Ms[s][lane * 4]) = pk;
    }
    __syncthreads();   // B2: Ms + seg_l ready

    f32x4 acc[2][8];
    #pragma unroll
    for (int i = 0; i < 2; ++i)
        #pragma unroll
        for (int j = 0; j < 8; ++j) acc[i][j] = (f32x4){0.f, 0.f, 0.f, 0.f};

    // ---- GEMM1: D row = h (A = WphT), col = token ----
    for (int kc8 = 0; kc8 < 8; ++kc8) {
        int kc = kc8 * 32;
        bf16x8 afc[2] = {afp[0], afp[1]};
        if (kc8 < 7)
            #pragma unroll
            for (int mf = 0; mf < 2; ++mf)
                afp[mf] = *reinterpret_cast<const bf16x8*>(WphT + (size_t)(mb + mf * 16 + cc) * HD + kc + 32 + quad * 8);
        #pragma unroll
        for (int nf = 0; nf < 8; ++nf) {
            bf16x8 bfr = *reinterpret_cast<const bf16x8*>(&Ah[nf * 16 + cc][kc + quad * 8]);
            acc[0][nf] = __builtin_amdgcn_mfma_f32_16x16x32_bf16(afc[0], bfr, acc[0][nf], 0, 0, 0);
            acc[1][nf] = __builtin_amdgcn_mfma_f32_16x16x32_bf16(afc[1], bfr, acc[1][nf], 0, 0, 0);
        }
    }

    // ---- u-GEMM: D[sess][n] = Ms @ W1T^T; sess = quad*4+r, n = mb+nf*16+cc ----
    f32x4 uacc[2];
    uacc[0] = (f32x4){0.f, 0.f, 0.f, 0.f};
    uacc[1] = (f32x4){0.f, 0.f, 0.f, 0.f};
    for (int kc8 = 0; kc8 < 8; ++kc8) {
        int kc = kc8 * 32;
        bf16x8 msf = *reinterpret_cast<const bf16x8*>(&Ms[cc][kc + quad * 8]);
        #pragma unroll
        for (int nf = 0; nf < 2; ++nf) {
            bf16x8 wf = *reinterpret_cast<const bf16x8*>(W1T + (size_t)(mb + nf * 16 + cc) * HD + kc + quad * 8);
            uacc[nf] = __builtin_amdgcn_mfma_f32_16x16x32_bf16(msf, wf, uacc[nf], 0, 0, 0);
        }
    }

    // preload GEMM2 weight frags kc=0 (in flight across the barrier)
    bf16x8 wfp[2];
    #pragma unroll
    for (int mf = 0; mf < 2; ++mf)
        wfp[mf] = *reinterpret_cast<const bf16x8*>(W2T + (size_t)(mb + mf * 16 + cc) * HD + quad * 8);
    __syncthreads();   // B3: all Ah/Ms reads done

    // ---- epilogue 1: Ph[token][h] = tanh(acc + P2[rp][h]) in place ----
    #pragma unroll
    for (int nf = 0; nf < 8; ++nf) {
        int token = nf * 16 + cc;
        const float* p2row = P2 + (size_t)rp_s[token] * HD;
        #pragma unroll
        for (int mf = 0; mf < 2; ++mf) {
            int h0 = mb + mf * 16 + quad * 4;
            const f32x4 p2v = *reinterpret_cast<const f32x4*>(p2row + h0);
            us4 pk;
            {
                float v0 = acc[mf][nf][0] + p2v[0];
                float v1 = acc[mf][nf][1] + p2v[1];
                float v2 = acc[mf][nf][2] + p2v[2];
                float v3 = acc[mf][nf][3] + p2v[3];
                float e0 = __expf(2.f * v0), e1 = __expf(2.f * v1);
                float e2 = __expf(2.f * v2), e3 = __expf(2.f * v3);
                pk[0] = f2bf(1.f - 2.f / (e0 + 1.f));
                pk[1] = f2bf(1.f - 2.f / (e1 + 1.f));
                pk[2] = f2bf(1.f - 2.f / (e2 + 1.f));
                pk[3] = f2bf(1.f - 2.f / (e3 + 1.f));
            }
            *reinterpret_cast<us4*>(&Ah[token][h0]) = pk;
            acc[mf][nf] = (f32x4){0.f, 0.f, 0.f, 0.f};
        }
    }
    __syncthreads();   // B4: Ph ready

    // ---- GEMM2: D row = n (A = W2T), col = token ----
    for (int kc8 = 0; kc8 < 8; ++kc8) {
        int kc = kc8 * 32;
        bf16x8 wfc[2] = {wfp[0], wfp[1]};
        if (kc8 < 7)
            #pragma unroll
            for (int mf = 0; mf < 2; ++mf)
                wfp[mf] = *reinterpret_cast<const bf16x8*>(W2T + (size_t)(mb + mf * 16 + cc) * HD + kc + 32 + quad * 8);
        #pragma unroll
        for (int nf = 0; nf < 8; ++nf) {
            bf16x8 af = *reinterpret_cast<const bf16x8*>(&Ah[nf * 16 + cc][kc + quad * 8]);
            acc[0][nf] = __builtin_amdgcn_mfma_f32_16x16x32_bf16(wfc[0], af, acc[0][nf], 0, 0, 0);
            acc[1][nf] = __builtin_amdgcn_mfma_f32_16x16x32_bf16(wfc[1], af, acc[1][nf], 0, 0, 0);
        }
    }
    __syncthreads();   // B5: Ph reads done, Ah storage reusable

    // ---- spill u to LDS overlay (over dead Ph): us[sess][n] = uacc + b1[n] + b2[n] ----
    float* usp = reinterpret_cast<float*>(&Ah[0][0]);
    {
        #pragma unroll
        for (int nf = 0; nf < 2; ++nf) {
            int n = mb + nf * 16 + cc;
            float b12 = b1[n] + b2[n];
            #pragma unroll
            for (int r = 0; r < 4; ++r)
                usp[(quad * 4 + r) * USTRIDE + n] = uacc[nf][r] + b12;
        }
    }
    __syncthreads();   // B6: us ready

    // ---- epilogue 2: alpha[token] += sum_n sigmoid(acc + us[seg][n]) * qw[n] ----
    f32x4 qv[2];
    #pragma unroll
    for (int mf = 0; mf < 2; ++mf)
        qv[mf] = *reinterpret_cast<const f32x4*>(qw + mb + mf * 16 + quad * 4);
    #pragma unroll
    for (int nf = 0; nf < 8; ++nf) {
        int token = nf * 16 + cc;
        int stok = seg_l[token];
        float s = 0.f;
        #pragma unroll
        for (int mf = 0; mf < 2; ++mf) {
            const f32x4 uv = *reinterpret_cast<const f32x4*>(&usp[stok * USTRIDE + mb + mf * 16 + quad * 4]);
            #pragma unroll
            for (int r = 0; r < 4; ++r) {
                float g = acc[mf][nf][r] + uv[r];
                g = 1.0f / (1.0f + __expf(-g));
                s += g * qv[mf][r];
            }
        }
        s += __shfl_xor(s, 16);
        s += __shfl_xor(s, 32);
        if (quad == 0) atomicAdd(&alpha_s[token], s);
    }
    __syncthreads();   // B7: alpha ready

    // ---- hs tail: out[b0+si][col] = sum_r alpha[r] * hidden_fp32[r][col]; sessions whole
    //      -> direct writes, no atomics. hidden rows are L2/LLC-hot from staging. ----
    {
        int col = tid & 255, p = tid >> 8;
        const float* hp = hidden + (size_t)t0g * HD + col;
        for (int si = p; si < nsess; si += 2) {
            int st = sess_st[si], en = sess_st[si + 1];
            float a0 = 0.f, a1 = 0.f;
            int r = st;
            for (; r + 1 < en; r += 2) {
                a0 += alpha_s[r]     * hp[(size_t)r * HD];
                a1 += alpha_s[r + 1] * hp[(size_t)(r + 1) * HD];
            }
            if (r < en) a0 += alpha_s[r] * hp[(size_t)r * HD];
            out[(size_t)(b0 + si) * HD + col] = a0 + a1;
        }
    }
}

extern "C" void kernel_launch(void* const* d_in, const int* in_sizes, int n_in,
                              void* d_out, int out_size, void* d_ws, size_t ws_size,
                              hipStream_t stream) {
    (void)n_in; (void)out_size; (void)ws_size;
    const float* hidden    = (const float*)d_in[0];
    const float* pos_table = (const float*)d_in[1];
    const float* W_pos     = (const float*)d_in[2];
    const float* b_pos     = (const float*)d_in[3];
    const float* W1        = (const float*)d_in[4];
    const float* b1        = (const float*)d_in[5];
    const float* W2        = (const float*)d_in[6];
    const float* b2        = (const float*)d_in[7];
    const float* qw        = (const float*)d_in[8];
    const float* qb        = (const float*)d_in[9];
    const int* seq_len     = (const int*)d_in[10];
    const int* reverse_pos = (const int*)d_in[11];

    int B  = in_sizes[10];
    int NP = in_sizes[1] / HD;

    char* ws = (char*)d_ws;
    auto carve = [&](size_t bytes) -> char* {
        char* p = ws;
        ws += (bytes + 255) & ~(size_t)255;
        return p;
    };
    int* offsets          = (int*)carve((size_t)(B + 1) * sizeof(int));
    int* grp_off          = (int*)carve((size_t)(B + 2) * sizeof(int));
    int* grp_meta         = (int*)carve(64);
    float* P2             = (float*)carve((size_t)NP * HD * sizeof(float));
    unsigned short* WphT  = (unsigned short*)carve((size_t)HD * HD * 2);
    unsigned short* WpbT  = (unsigned short*)carve((size_t)HD * HD * 2);
    unsigned short* W1T   = (unsigned short*)carve((size_t)HD * HD * 2);
    unsigned short* W2T   = (unsigned short*)carve((size_t)HD * HD * 2);

    prep_kernel<<<65, 256, 0, stream>>>(seq_len, offsets, B, grp_off, grp_meta,
                                        W_pos, W1, W2, WphT, WpbT, W1T, W2T);
    p2_kernel<<<(NP + 15) / 16, 256, 0, stream>>>(pos_table, NP, WpbT, b_pos, P2);
    main_kernel<<<B, 512, 0, stream>>>(hidden, WphT, W1T, W2T, P2, b1, b2, qw, qb,
                                       reverse_pos, offsets, grp_off, grp_meta,
                                       (float*)d_out);
}